// Round 4
// baseline (142.565 us; speedup 1.0000x reference)
//
#include <hip/hip_runtime.h>
#include <hip/hip_bf16.h>
#include <math.h>

typedef _Float16 f16x8 __attribute__((ext_vector_type(8)));
typedef float f32x4 __attribute__((ext_vector_type(4)));

// ---------------- gate helpers (per-wave, lane = row of 64-dim state) ----------------

__device__ __forceinline__ void rot_gate(float& re, float& im, int r, int bit, float th) {
  float s, c;
  __sincosf(th, &s, &c);
  if ((r >> bit) & 1) {
    float nr = re * c - im * s;
    float ni = re * s + im * c;
    re = nr; im = ni;
  }
}

__device__ __forceinline__ void sq_gate(float& re, float& im, int r, int bit, float rr) {
  float u = __expf(-fabsf(rr));
  float sech = 2.0f * u / (1.0f + u * u);
  float f0 = sqrtf(sech);
  float f1 = sech * f0;
  float m = ((r >> bit) & 1) ? f1 : f0;
  re *= m; im *= m;
}

__device__ __forceinline__ void disp_gate(float& re, float& im, int r, int bit, float a) {
  // D(a) real a, truncated: pref*[[1,-a],[a,1-a^2]]
  float pref = __expf(-0.5f * a * a);
  float pre = __shfl_xor(re, 1 << bit, 64);
  float pim = __shfl_xor(im, 1 << bit, 64);
  int b = (r >> bit) & 1;
  float A = pref * (b ? (1.0f - a * a) : 1.0f);
  float B = pref * (b ? a : -a);
  re = A * re + B * pre;
  im = A * im + B * pim;
}

__device__ __forceinline__ void bs_gate(float& re, float& im, int r, int bita, int bitb,
                                        float th, float ph) {
  float s, c;  __sincosf(th, &s, &c);
  float sp, cp; __sincosf(ph, &sp, &cp);
  float c2 = c * c - s * s;  // cos(2*theta)
  int na = (r >> bita) & 1;
  int nb = (r >> bitb) & 1;
  int mask = (1 << bita) | (1 << bitb);
  float pre = __shfl_xor(re, mask, 64);
  float pim = __shfl_xor(im, mask, 64);
  float A, Tr, Ti;
  if (na == nb) {
    A = na ? c2 : 1.0f; Tr = 0.0f; Ti = 0.0f;
  } else {
    A = c;
    Tr = na ? (-s * cp) : (s * cp);
    Ti = s * sp;
  }
  float nr = A * re + Tr * pre - Ti * pim;
  float ni = A * im + Tr * pim + Ti * pre;
  re = nr; im = ni;
}

// ---------------- setup: build M (64x64 complex) in LDS, pack W f16 A-fragments ----------
// One block, 16 waves. Wave v computes columns 4v..4v+3 (lane = row, gates via shfl_xor).
// Then packs W = [Mr -Mi; Mi Mr] into mfma_f32_16x16x32_f16 A-fragment order:
// Wp[((rt*4+kk)*64 + lane)*8 + j] = W[rt*16 + (lane&15)][kk*32 + (lane>>4)*8 + j].

__global__ __launch_bounds__(1024) void build_pack(const float* __restrict__ var,
                                                   _Float16* __restrict__ Wp) {
  __shared__ float2 Msh[4096];  // 32 KB, row-major [r][c]
  const int t = threadIdx.x;
  const int wv = t >> 6;
  const int r = t & 63;

  for (int i = 0; i < 4; ++i) {
    const int c = wv * 4 + i;
    float re = (r == c) ? 1.0f : 0.0f;
    float im = 0.0f;
    for (int l = 0; l < 2; ++l) {
      const float* v = var + l * 50;
      for (int g = 0; g < 5; ++g) bs_gate(re, im, r, 5 - g, 4 - g, v[2 * g], v[2 * g + 1]);
      for (int w = 0; w < 6; ++w) rot_gate(re, im, r, 5 - w, v[10 + w]);
      for (int w = 0; w < 6; ++w) sq_gate(re, im, r, 5 - w, v[16 + w]);
      for (int g = 0; g < 5; ++g) bs_gate(re, im, r, 5 - g, 4 - g, v[22 + 2 * g], v[23 + 2 * g]);
      for (int w = 0; w < 6; ++w) rot_gate(re, im, r, 5 - w, v[32 + w]);
      for (int w = 0; w < 6; ++w) disp_gate(re, im, r, 5 - w, v[38 + w]);
      for (int w = 0; w < 6; ++w) rot_gate(re, im, r, 5 - w, v[44 + w]);  // Kerr == rot at cutoff 2
    }
    Msh[r * 64 + c] = make_float2(re, im);
  }
  __syncthreads();

  for (int idx = t; idx < 2048; idx += 1024) {
    int lane = idx & 63;
    int kk = (idx >> 6) & 3;
    int rt = idx >> 8;
    int m = rt * 16 + (lane & 15);
    int k0 = kk * 32 + (lane >> 4) * 8;
    f16x8 h;
    #pragma unroll
    for (int j = 0; j < 8; ++j) {
      int k = k0 + j;
      float v;
      if (m < 64) {
        v = (k < 64) ? Msh[m * 64 + k].x : -Msh[m * 64 + (k - 64)].y;
      } else {
        v = (k < 64) ? Msh[(m - 64) * 64 + k].y : Msh[(m - 64) * 64 + (k - 64)].x;
      }
      h[j] = (_Float16)v;
    }
    *(f16x8*)(Wp + (size_t)idx * 8) = h;
  }
}

// ---------------- main kernel: 256 threads = 4 waves, 64 samples per block ----------------
// GEMM formulation: Amp(128 x N) = W(128x128) x V(128 x N), V = [Re a; Im a] per sample.
// 4 threads per sample build the product state straight into B-fragment-packed LDS
// (B-frag: lane l holds B[k=(l>>4)*8+j][n=l&15]); each wave MFMAs 16 samples x 128 rows.
// A-fragments read directly from global Wp (32 KB, L1-resident) -> LDS = 33 KB -> 4 blocks/CU.
// C/D layout (col=lane&15,row=(lane>>4)*4+reg) puts Re(row-tile rt) and Im(rt+4) of the
// same output element in the same lane -> prob, residual, LN, store all in-register.

__global__ __launch_bounds__(256, 4) void ff_main(const float* __restrict__ x,
                                                  const float* __restrict__ gamma,
                                                  const float* __restrict__ beta,
                                                  const _Float16* __restrict__ Wp,
                                                  float* __restrict__ out) {
  __shared__ __align__(16) _Float16 Sl[8192];    // 16 KB packed state B-fragments (4 waves)
  __shared__ float xl[64 * 65];                  // 16.6 KB x tile (+1 pad)

  const int t = threadIdx.x;
  const size_t base = (size_t)blockIdx.x * (64 * 64);

  // ---- stage x tile (16 KB), coalesced ----
  {
    const float4* xv = (const float4*)(x + base);
    #pragma unroll
    for (int i = 0; i < 4; ++i) {
      int ci = i * 256 + t;
      float4 q = xv[ci];
      int fi = ci * 4;
      int s = fi >> 6;
      int j = fi & 63;
      float* row = &xl[s * 65 + j];
      row[0] = q.x; row[1] = q.y; row[2] = q.z; row[3] = q.w;
    }
  }
  __syncthreads();

  // ---- state build: thread (s = t>>2, p = t&3) computes a[p*16 .. p*16+15] ----
  {
    const int s = t >> 2, p = t & 3;
    const float* X = &xl[s * 65];

    float t0[6], t1r[6], t1i[6];
    #pragma unroll
    for (int w = 0; w < 6; ++w) {
      float r1  = X[2 * w];
      float rd  = X[28 + 2 * w];
      float pd  = X[29 + 2 * w];
      float kk_ = X[40 + w];
      float r2  = X[46 + 2 * w];
      float th2 = X[58 + w];
      float u1 = __expf(-fabsf(r1));
      float sech1 = 2.0f * u1 / (1.0f + u1 * u1);
      float u2 = __expf(-fabsf(r2));
      float sech2 = 2.0f * u2 / (1.0f + u2 * u2);
      float s1h = sqrtf(sech1);
      float s2h = sqrtf(sech2);
      float pref = __expf(-0.5f * rd * rd);
      float c0 = s1h * pref;
      t0[w] = c0 * s2h;
      float m1 = c0 * rd * sech2 * s2h;
      float ph = pd + kk_ + th2;
      float sp, cp;
      __sincosf(ph, &sp, &cp);
      t1r[w] = m1 * cp;
      t1i[w] = m1 * sp;
    }

    // prefix over wires 0 (bit5 = p>>1) and 1 (bit4 = p&1)
    float pr, pi;
    {
      int b0 = (p >> 1) & 1, b1 = p & 1;
      float a0r = b0 ? t1r[0] : t0[0];
      float a0i = b0 ? t1i[0] : 0.0f;
      float a1r = b1 ? t1r[1] : t0[1];
      float a1i = b1 ? t1i[1] : 0.0f;
      pr = a0r * a1r - a0i * a1i;
      pi = a0r * a1i + a0i * a1r;
    }

    // tensor-double wires 5,4,3,2 into bits 0..3 of the 16-chunk
    float tr[16], ti[16];
    tr[0] = pr; ti[0] = pi;
    #pragma unroll
    for (int st = 0; st < 4; ++st) {
      const int w = 5 - st;
      const int half = 1 << st;
      #pragma unroll
      for (int n = 0; n < half; ++n) {
        float br = tr[n], bi = ti[n];
        tr[n + half] = br * t1r[w] - bi * t1i[w];
        ti[n + half] = br * t1i[w] + bi * t1r[w];
        tr[n] = br * t0[w];
        ti[n] = bi * t0[w];
      }
    }

    // write B-fragment-packed halves: Re rows k=p*16+i (kk=p>>1), Im rows k=64+p*16+i (+2)
    const int ws_ = s >> 4, c = s & 15;
    const int kkre = p >> 1;
    #pragma unroll
    for (int j8 = 0; j8 < 2; ++j8) {
      const int q = ((p & 1) << 1) + j8;
      f16x8 hre, him;
      #pragma unroll
      for (int j = 0; j < 8; ++j) {
        hre[j] = (_Float16)tr[j8 * 8 + j];
        him[j] = (_Float16)ti[j8 * 8 + j];
      }
      *(f16x8*)&Sl[(size_t)((ws_ * 4 + kkre) * 64 + q * 16 + c) * 8] = hre;
      *(f16x8*)&Sl[(size_t)((ws_ * 4 + kkre + 2) * 64 + q * 16 + c) * 8] = him;
    }
  }
  __syncthreads();

  // ---- GEMM: wave w -> samples w*16..w*16+15, all 128 output rows ----
  const int w = t >> 6;
  const int lane = t & 63;
  const int q = lane >> 4;
  const int c = lane & 15;

  const f16x8* Wf = (const f16x8*)Wp;

  f32x4 acc[8];
  #pragma unroll
  for (int rt = 0; rt < 8; ++rt) acc[rt] = (f32x4){0.0f, 0.0f, 0.0f, 0.0f};

  #pragma unroll
  for (int kk = 0; kk < 4; ++kk) {
    f16x8 b = *(const f16x8*)&Sl[(size_t)((w * 4 + kk) * 64 + lane) * 8];
    #pragma unroll
    for (int rt = 0; rt < 8; ++rt) {
      f16x8 a = Wf[(size_t)(rt * 4 + kk) * 64 + lane];
      acc[rt] = __builtin_amdgcn_mfma_f32_16x16x32_f16(a, b, acc[rt], 0, 0, 0);
    }
  }

  // ---- epilogue: prob = re^2+im^2, residual, LayerNorm (shuffle reduce), store ----
  const int s = w * 16 + c;
  float y[4][4];
  float s1 = 0.0f, s2 = 0.0f;
  #pragma unroll
  for (int rt = 0; rt < 4; ++rt) {
    #pragma unroll
    for (int reg = 0; reg < 4; ++reg) {
      float re = acc[rt][reg];
      float im = acc[rt + 4][reg];
      int j = rt * 16 + q * 4 + reg;
      float yy = fmaf(re, re, im * im) + xl[s * 65 + j];
      y[rt][reg] = yy;
      s1 += yy;
      s2 += yy * yy;
    }
  }
  s1 += __shfl_xor(s1, 16, 64); s1 += __shfl_xor(s1, 32, 64);
  s2 += __shfl_xor(s2, 16, 64); s2 += __shfl_xor(s2, 32, 64);
  float mu = s1 * (1.0f / 64.0f);
  float inv = rsqrtf(fmaf(s2, 1.0f / 64.0f, -mu * mu) + 1e-5f);

  #pragma unroll
  for (int rt = 0; rt < 4; ++rt) {
    int j0 = rt * 16 + q * 4;
    float4 g = *(const float4*)(gamma + j0);
    float4 bb = *(const float4*)(beta + j0);
    float4 o;
    o.x = (y[rt][0] - mu) * inv * g.x + bb.x;
    o.y = (y[rt][1] - mu) * inv * g.y + bb.y;
    o.z = (y[rt][2] - mu) * inv * g.z + bb.z;
    o.w = (y[rt][3] - mu) * inv * g.w + bb.w;
    *(float4*)(out + base + (size_t)s * 64 + j0) = o;
  }
}

extern "C" void kernel_launch(void* const* d_in, const int* in_sizes, int n_in,
                              void* d_out, int out_size, void* d_ws, size_t ws_size,
                              hipStream_t stream) {
  const float* x     = (const float*)d_in[0];
  const float* var   = (const float*)d_in[1];
  const float* gamma = (const float*)d_in[2];
  const float* beta  = (const float*)d_in[3];
  float* out = (float*)d_out;

  _Float16* Wp = (_Float16*)d_ws;  // 32 KB packed f16 A-fragments

  build_pack<<<1, 1024, 0, stream>>>(var, Wp);

  int nsamples = in_sizes[0] / 64;     // 131072
  int blocks = nsamples / 64;          // 2048
  ff_main<<<blocks, 256, 0, stream>>>(x, gamma, beta, Wp, out);
}

// Round 5
// 103.794 us; speedup vs baseline: 1.3735x; 1.3735x over previous
//
#include <hip/hip_runtime.h>
#include <hip/hip_bf16.h>
#include <math.h>

typedef _Float16 f16x8 __attribute__((ext_vector_type(8)));
typedef float f32x4 __attribute__((ext_vector_type(4)));

// ---------------- gate helpers (per-wave, lane = row of 64-dim state) ----------------

__device__ __forceinline__ void rot_gate(float& re, float& im, int r, int bit, float th) {
  float s, c;
  __sincosf(th, &s, &c);
  if ((r >> bit) & 1) {
    float nr = re * c - im * s;
    float ni = re * s + im * c;
    re = nr; im = ni;
  }
}

__device__ __forceinline__ void sq_gate(float& re, float& im, int r, int bit, float rr) {
  float u = __expf(-fabsf(rr));
  float sech = 2.0f * u / (1.0f + u * u);
  float f0 = sqrtf(sech);
  float f1 = sech * f0;
  float m = ((r >> bit) & 1) ? f1 : f0;
  re *= m; im *= m;
}

__device__ __forceinline__ void disp_gate(float& re, float& im, int r, int bit, float a) {
  // D(a) real a, truncated: pref*[[1,-a],[a,1-a^2]]
  float pref = __expf(-0.5f * a * a);
  float pre = __shfl_xor(re, 1 << bit, 64);
  float pim = __shfl_xor(im, 1 << bit, 64);
  int b = (r >> bit) & 1;
  float A = pref * (b ? (1.0f - a * a) : 1.0f);
  float B = pref * (b ? a : -a);
  re = A * re + B * pre;
  im = A * im + B * pim;
}

__device__ __forceinline__ void bs_gate(float& re, float& im, int r, int bita, int bitb,
                                        float th, float ph) {
  float s, c;  __sincosf(th, &s, &c);
  float sp, cp; __sincosf(ph, &sp, &cp);
  float c2 = c * c - s * s;  // cos(2*theta)
  int na = (r >> bita) & 1;
  int nb = (r >> bitb) & 1;
  int mask = (1 << bita) | (1 << bitb);
  float pre = __shfl_xor(re, mask, 64);
  float pim = __shfl_xor(im, mask, 64);
  float A, Tr, Ti;
  if (na == nb) {
    A = na ? c2 : 1.0f; Tr = 0.0f; Ti = 0.0f;
  } else {
    A = c;
    Tr = na ? (-s * cp) : (s * cp);
    Ti = s * sp;
  }
  float nr = A * re + Tr * pre - Ti * pim;
  float ni = A * im + Tr * pim + Ti * pre;
  re = nr; im = ni;
}

// ---------------- setup: 64 blocks x 64 lanes, column c per block, scatter-pack Wp ------
// Block c, lane r ends with M[r][c] = (re, im). W = [Mr -Mi; Mi Mr] (128x128 f16) in
// mfma_f32_16x16x32_f16 A-fragment order:
//   element (m,k) lives at Wp[((m>>4)*4 + (k>>5))*64 + ((m&15) | (((k>>3)&3)<<4))]*8 + (k&7).
// Column c of M supplies exactly (r,c,re),(r+64,c,im),(r,64+c,-im),(r+64,64+c,re).
// 64 CUs in parallel, ~136 transcendental wave-instrs each (R4's single-block fusion put
// 8.7k of them on ONE CU = 46 us serial bottleneck).

__global__ __launch_bounds__(64) void build_M_pack(const float* __restrict__ var,
                                                   _Float16* __restrict__ Wp) {
  const int c = blockIdx.x;   // column (input basis state)
  const int r = threadIdx.x;  // row (amplitude index); wire w <-> bit (5-w)
  float re = (r == c) ? 1.0f : 0.0f;
  float im = 0.0f;
  for (int l = 0; l < 2; ++l) {
    const float* v = var + l * 50;
    for (int g = 0; g < 5; ++g) bs_gate(re, im, r, 5 - g, 4 - g, v[2 * g], v[2 * g + 1]);
    for (int w = 0; w < 6; ++w) rot_gate(re, im, r, 5 - w, v[10 + w]);
    for (int w = 0; w < 6; ++w) sq_gate(re, im, r, 5 - w, v[16 + w]);
    for (int g = 0; g < 5; ++g) bs_gate(re, im, r, 5 - g, 4 - g, v[22 + 2 * g], v[23 + 2 * g]);
    for (int w = 0; w < 6; ++w) rot_gate(re, im, r, 5 - w, v[32 + w]);
    for (int w = 0; w < 6; ++w) disp_gate(re, im, r, 5 - w, v[38 + w]);
    for (int w = 0; w < 6; ++w) rot_gate(re, im, r, 5 - w, v[44 + w]);  // Kerr == rot at cutoff 2
  }

  auto store = [&](int m, int k, float v) {
    int rt = m >> 4;
    int kk = k >> 5;
    int lane = (m & 15) | (((k >> 3) & 3) << 4);
    int j = k & 7;
    Wp[(size_t)(((rt * 4 + kk) * 64 + lane) * 8 + j)] = (_Float16)v;
  };
  store(r,      c,      re);
  store(r + 64, c,      im);
  store(r,      64 + c, -im);
  store(r + 64, 64 + c, re);
}

// ---------------- main kernel: 256 threads = 4 waves, 64 samples per block ----------------
// GEMM formulation: Amp(128 x N) = W(128x128) x V(128 x N), V = [Re a; Im a] per sample.
// 4 threads per sample build the product state straight into B-fragment-packed LDS
// (B-frag: lane l holds B[k=(l>>4)*8+j][n=l&15]); each wave MFMAs 16 samples x 128 rows.
// A-fragments read directly from global Wp (32 KB, L1-resident) -> LDS = 33 KB -> 4 blocks/CU.
// C/D layout (col=lane&15,row=(lane>>4)*4+reg) puts Re(row-tile rt) and Im(rt+4) of the
// same output element in the same lane -> prob, residual, LN, store all in-register.

__global__ __launch_bounds__(256, 4) void ff_main(const float* __restrict__ x,
                                                  const float* __restrict__ gamma,
                                                  const float* __restrict__ beta,
                                                  const _Float16* __restrict__ Wp,
                                                  float* __restrict__ out) {
  __shared__ __align__(16) _Float16 Sl[8192];    // 16 KB packed state B-fragments (4 waves)
  __shared__ float xl[64 * 65];                  // 16.6 KB x tile (+1 pad)

  const int t = threadIdx.x;
  const size_t base = (size_t)blockIdx.x * (64 * 64);

  // ---- stage x tile (16 KB), coalesced ----
  {
    const float4* xv = (const float4*)(x + base);
    #pragma unroll
    for (int i = 0; i < 4; ++i) {
      int ci = i * 256 + t;
      float4 q = xv[ci];
      int fi = ci * 4;
      int s = fi >> 6;
      int j = fi & 63;
      float* row = &xl[s * 65 + j];
      row[0] = q.x; row[1] = q.y; row[2] = q.z; row[3] = q.w;
    }
  }
  __syncthreads();

  // ---- state build: thread (s = t>>2, p = t&3) computes a[p*16 .. p*16+15] ----
  {
    const int s = t >> 2, p = t & 3;
    const float* X = &xl[s * 65];

    float t0[6], t1r[6], t1i[6];
    #pragma unroll
    for (int w = 0; w < 6; ++w) {
      float r1  = X[2 * w];
      float rd  = X[28 + 2 * w];
      float pd  = X[29 + 2 * w];
      float kk_ = X[40 + w];
      float r2  = X[46 + 2 * w];
      float th2 = X[58 + w];
      float u1 = __expf(-fabsf(r1));
      float sech1 = 2.0f * u1 / (1.0f + u1 * u1);
      float u2 = __expf(-fabsf(r2));
      float sech2 = 2.0f * u2 / (1.0f + u2 * u2);
      float s1h = sqrtf(sech1);
      float s2h = sqrtf(sech2);
      float pref = __expf(-0.5f * rd * rd);
      float c0 = s1h * pref;
      t0[w] = c0 * s2h;
      float m1 = c0 * rd * sech2 * s2h;
      float ph = pd + kk_ + th2;
      float sp, cp;
      __sincosf(ph, &sp, &cp);
      t1r[w] = m1 * cp;
      t1i[w] = m1 * sp;
    }

    // prefix over wires 0 (bit5 = p>>1) and 1 (bit4 = p&1)
    float pr, pi;
    {
      int b0 = (p >> 1) & 1, b1 = p & 1;
      float a0r = b0 ? t1r[0] : t0[0];
      float a0i = b0 ? t1i[0] : 0.0f;
      float a1r = b1 ? t1r[1] : t0[1];
      float a1i = b1 ? t1i[1] : 0.0f;
      pr = a0r * a1r - a0i * a1i;
      pi = a0r * a1i + a0i * a1r;
    }

    // tensor-double wires 5,4,3,2 into bits 0..3 of the 16-chunk
    float tr[16], ti[16];
    tr[0] = pr; ti[0] = pi;
    #pragma unroll
    for (int st = 0; st < 4; ++st) {
      const int w = 5 - st;
      const int half = 1 << st;
      #pragma unroll
      for (int n = 0; n < half; ++n) {
        float br = tr[n], bi = ti[n];
        tr[n + half] = br * t1r[w] - bi * t1i[w];
        ti[n + half] = br * t1i[w] + bi * t1r[w];
        tr[n] = br * t0[w];
        ti[n] = bi * t0[w];
      }
    }

    // write B-fragment-packed halves: Re rows k=p*16+i (kk=p>>1), Im rows k=64+p*16+i (+2)
    const int ws_ = s >> 4, c = s & 15;
    const int kkre = p >> 1;
    #pragma unroll
    for (int j8 = 0; j8 < 2; ++j8) {
      const int q = ((p & 1) << 1) + j8;
      f16x8 hre, him;
      #pragma unroll
      for (int j = 0; j < 8; ++j) {
        hre[j] = (_Float16)tr[j8 * 8 + j];
        him[j] = (_Float16)ti[j8 * 8 + j];
      }
      *(f16x8*)&Sl[(size_t)((ws_ * 4 + kkre) * 64 + q * 16 + c) * 8] = hre;
      *(f16x8*)&Sl[(size_t)((ws_ * 4 + kkre + 2) * 64 + q * 16 + c) * 8] = him;
    }
  }
  __syncthreads();

  // ---- GEMM: wave w -> samples w*16..w*16+15, all 128 output rows ----
  const int w = t >> 6;
  const int lane = t & 63;
  const int q = lane >> 4;
  const int c = lane & 15;

  const f16x8* Wf = (const f16x8*)Wp;

  f32x4 acc[8];
  #pragma unroll
  for (int rt = 0; rt < 8; ++rt) acc[rt] = (f32x4){0.0f, 0.0f, 0.0f, 0.0f};

  #pragma unroll
  for (int kk = 0; kk < 4; ++kk) {
    f16x8 b = *(const f16x8*)&Sl[(size_t)((w * 4 + kk) * 64 + lane) * 8];
    #pragma unroll
    for (int rt = 0; rt < 8; ++rt) {
      f16x8 a = Wf[(size_t)(rt * 4 + kk) * 64 + lane];
      acc[rt] = __builtin_amdgcn_mfma_f32_16x16x32_f16(a, b, acc[rt], 0, 0, 0);
    }
  }

  // ---- epilogue: prob = re^2+im^2, residual, LayerNorm (shuffle reduce), store ----
  const int s = w * 16 + c;
  float y[4][4];
  float s1 = 0.0f, s2 = 0.0f;
  #pragma unroll
  for (int rt = 0; rt < 4; ++rt) {
    #pragma unroll
    for (int reg = 0; reg < 4; ++reg) {
      float re = acc[rt][reg];
      float im = acc[rt + 4][reg];
      int j = rt * 16 + q * 4 + reg;
      float yy = fmaf(re, re, im * im) + xl[s * 65 + j];
      y[rt][reg] = yy;
      s1 += yy;
      s2 += yy * yy;
    }
  }
  s1 += __shfl_xor(s1, 16, 64); s1 += __shfl_xor(s1, 32, 64);
  s2 += __shfl_xor(s2, 16, 64); s2 += __shfl_xor(s2, 32, 64);
  float mu = s1 * (1.0f / 64.0f);
  float inv = rsqrtf(fmaf(s2, 1.0f / 64.0f, -mu * mu) + 1e-5f);

  #pragma unroll
  for (int rt = 0; rt < 4; ++rt) {
    int j0 = rt * 16 + q * 4;
    float4 g = *(const float4*)(gamma + j0);
    float4 bb = *(const float4*)(beta + j0);
    float4 o;
    o.x = (y[rt][0] - mu) * inv * g.x + bb.x;
    o.y = (y[rt][1] - mu) * inv * g.y + bb.y;
    o.z = (y[rt][2] - mu) * inv * g.z + bb.z;
    o.w = (y[rt][3] - mu) * inv * g.w + bb.w;
    *(float4*)(out + base + (size_t)s * 64 + j0) = o;
  }
}

extern "C" void kernel_launch(void* const* d_in, const int* in_sizes, int n_in,
                              void* d_out, int out_size, void* d_ws, size_t ws_size,
                              hipStream_t stream) {
  const float* x     = (const float*)d_in[0];
  const float* var   = (const float*)d_in[1];
  const float* gamma = (const float*)d_in[2];
  const float* beta  = (const float*)d_in[3];
  float* out = (float*)d_out;

  _Float16* Wp = (_Float16*)d_ws;  // 32 KB packed f16 A-fragments

  build_M_pack<<<64, 64, 0, stream>>>(var, Wp);

  int nsamples = in_sizes[0] / 64;     // 131072
  int blocks = nsamples / 64;          // 2048
  ff_main<<<blocks, 256, 0, stream>>>(x, gamma, beta, Wp, out);
}